// Round 2
// baseline (397.054 us; speedup 1.0000x reference)
//
#include <hip/hip_runtime.h>
#include <hip/hip_bf16.h>

#define NN 8192
#define CIN 256
#define COUT 128
#define GR 32
#define GKT 64
#define CH 8            // i-chunks
#define ICH (NN / CH)   // 1024 rows per chunk
#define KT 64           // i-rows per step
#define NSTEP (ICH / KT)
#define HTS 72          // htS row stride in u16 (144 B: 16B-aligned, 9 quads -> b128 conflict-free)

typedef unsigned short u16;
typedef _Float16 f16;
typedef __attribute__((ext_vector_type(8))) short short8;
typedef __attribute__((ext_vector_type(8))) _Float16 f16x8;
typedef __attribute__((ext_vector_type(16))) float f32x16;

__device__ __forceinline__ short8 pack8_bf16(const float* v) {
    union { __hip_bfloat162 b2[4]; short8 s; } u;
    #pragma unroll
    for (int q = 0; q < 4; ++q)
        u.b2[q] = __float22bfloat162_rn(make_float2(v[2 * q], v[2 * q + 1]));
    return u.s;
}

// ---------------- Kernel A: h = x @ W (fp32) + fused attention-dot epilogue
// Unchanged verified GEMM body. Epilogue writes exp-tables instead of raw
// a_src: es1=e^s, es2=e^{0.2 s} (removes all transcendentals from kernel B's
// inner loop: exp(lrelu(s+d)) = es1*ed1 if es1*ed1>1 else es2*ed2).
__global__ __launch_bounds__(256) void gemm_h(const float* __restrict__ x,
                                              const float* __restrict__ W,
                                              const float* __restrict__ att_src,
                                              const float* __restrict__ att_dst,
                                              u16* __restrict__ h_t,
                                              float* __restrict__ es1,
                                              float* __restrict__ es2,
                                              float* __restrict__ a_dst) {
    __shared__ float Wt[GKT * COUT];      // 32 KB
    __shared__ float xt[GKT][GR + 4];     // 9 KB, transposed [k][r]
    __shared__ float ot[GR][COUT + 4];    // 16.5 KB transpose staging
    int tid = threadIdx.x;
    int i0 = blockIdx.x * GR;
    int tx = tid & 31, ty = tid >> 5;
    int c0 = tx * 4, r0 = ty * 4;
    int xr = tid >> 3, xk = (tid & 7) * 8;
    float acc[4][4] = {};

    for (int kt = 0; kt < CIN; kt += GKT) {
        float4 wv[8];
        #pragma unroll
        for (int j = 0; j < 8; ++j) {
            int f = j * 256 + tid;
            wv[j] = *(const float4*)&W[(size_t)(kt + (f >> 5)) * COUT + (f & 31) * 4];
        }
        float4 xv0 = *(const float4*)&x[(size_t)(i0 + xr) * CIN + kt + xk];
        float4 xv1 = *(const float4*)&x[(size_t)(i0 + xr) * CIN + kt + xk + 4];
        __syncthreads();
        #pragma unroll
        for (int j = 0; j < 8; ++j)
            *(float4*)&Wt[(j * 256 + tid) * 4] = wv[j];
        xt[xk + 0][xr] = xv0.x; xt[xk + 1][xr] = xv0.y;
        xt[xk + 2][xr] = xv0.z; xt[xk + 3][xr] = xv0.w;
        xt[xk + 4][xr] = xv1.x; xt[xk + 5][xr] = xv1.y;
        xt[xk + 6][xr] = xv1.z; xt[xk + 7][xr] = xv1.w;
        __syncthreads();
        #pragma unroll 8
        for (int k = 0; k < GKT; ++k) {
            float4 wk = *(const float4*)&Wt[k * COUT + c0];
            float4 xf = *(const float4*)&xt[k][r0];
            float xa[4] = {xf.x, xf.y, xf.z, xf.w};
            #pragma unroll
            for (int a = 0; a < 4; ++a) {
                acc[a][0] += xa[a] * wk.x; acc[a][1] += xa[a] * wk.y;
                acc[a][2] += xa[a] * wk.z; acc[a][3] += xa[a] * wk.w;
            }
        }
    }

    float4 asv = *(const float4*)&att_src[c0];
    float4 adv = *(const float4*)&att_dst[c0];
    #pragma unroll
    for (int a = 0; a < 4; ++a) {
        float4 o = make_float4(acc[a][0], acc[a][1], acc[a][2], acc[a][3]);
        *(float4*)&ot[r0 + a][c0] = o;
        float s = o.x * asv.x + o.y * asv.y + o.z * asv.z + o.w * asv.w;
        float d = o.x * adv.x + o.y * adv.y + o.z * adv.z + o.w * adv.w;
        #pragma unroll
        for (int m = 16; m >= 1; m >>= 1) {
            s += __shfl_xor(s, m, 32);
            d += __shfl_xor(d, m, 32);
        }
        if (tx == 0) {
            es1[i0 + r0 + a] = __expf(s);
            es2[i0 + r0 + a] = __expf(0.2f * s);
            a_dst[i0 + r0 + a] = d;
        }
    }
    __syncthreads();
    // transpose-out: thread -> (c, i-half of 16), two 16 B bf16 stores
    int c = tid >> 1, hf = tid & 1;
    float vals[16];
    #pragma unroll
    for (int q = 0; q < 16; ++q) vals[q] = ot[hf * 16 + q][c];
    *(short8*)(h_t + (size_t)c * NN + i0 + hf * 16)     = pack8_bf16(vals);
    *(short8*)(h_t + (size_t)c * NN + i0 + hf * 16 + 8) = pack8_bf16(vals + 8);
}

// ---------------- Kernel B: fused masked-GEMM (MFMA), v2 -------------------
// R6 was stall-bound (~0.75 TB/s effective on the 268 MB adj stream): the
// gload_lds A-staging forced a vmcnt(0) drain at every __syncthreads with
// only 2 blocks/CU to overlap. v2:
//  - adj read DIRECTLY per-lane (used once, only for !=0 test): each wave64
//    dword-load covers 2x128 B dense row segments; 32 independent HBM loads
//    per lane per step give MLP for latency hiding; no LDS, no drain.
//  - h_t tile double-buffered in LDS via reg-staging: prefetch step s+1's
//    regs before compute of s, ds_write after compute -> ONE barrier/step.
//  - exp-free inner loop: pv = mask ? (es1*ed1 > 1 ? es1*ed1 : es2*ed2) : 0.
// LDS: 36 KB (2x htS) + 8 KB exp tables = 44 KB -> 3 blocks/CU if VGPR <=168.
__global__ __launch_bounds__(256) void gat_mm(const float* __restrict__ adj,
                                              const u16* __restrict__ h_t,
                                              const float* __restrict__ es1,
                                              const float* __restrict__ es2,
                                              const float* __restrict__ a_dst,
                                              f16* __restrict__ pout,
                                              float* __restrict__ pden) {
    __shared__ u16 htS[2][128 * HTS];   // 2 x 18 KB, [c][i] stride 72
    __shared__ float e1S[ICH];          // 4 KB: e^{s_i}
    __shared__ float e2S[ICH];          // 4 KB: e^{0.2 s_i}
    int tid = threadIdx.x;
    int lane = tid & 63, w = tid >> 6;
    int jb = blockIdx.x & 63, ch = blockIdx.x >> 6;
    int j0 = jb * 128;
    int i0 = ch * ICH;
    int half = lane >> 5;
    int jloc = w * 32 + (lane & 31);
    int gj = j0 + jloc;
    float dj = a_dst[gj];
    float ed1 = __expf(dj), ed2 = __expf(0.2f * dj);

    ((float4*)e1S)[tid] = ((const float4*)(es1 + i0))[tid];
    ((float4*)e2S)[tid] = ((const float4*)(es2 + i0))[tid];

    // prologue: stage B(0) into buffer 0
    short8 bv[4];
    #pragma unroll
    for (int q = 0; q < 4; ++q) {
        int p = q * 256 + tid;
        bv[q] = *(const short8*)(h_t + (size_t)(p >> 3) * NN + i0 + (p & 7) * 8);
    }
    #pragma unroll
    for (int q = 0; q < 4; ++q) {
        int p = q * 256 + tid;
        *(short8*)(&htS[0][(p >> 3) * HTS + (p & 7) * 8]) = bv[q];
    }

    f32x16 acc[4];
    #pragma unroll
    for (int nt = 0; nt < 4; ++nt)
        #pragma unroll
        for (int q = 0; q < 16; ++q) acc[nt][q] = 0.f;
    float dsum = 0.f;
    __syncthreads();

    for (int s = 0; s < NSTEP; ++s) {
        int pb = s & 1;
        int ib = i0 + s * KT;
        // prefetch next B tile to regs (wraps on last iter; values unused)
        int ibn = i0 + ((s + 1) & (NSTEP - 1)) * KT;
        #pragma unroll
        for (int q = 0; q < 4; ++q) {
            int p = q * 256 + tid;
            bv[q] = *(const short8*)(h_t + (size_t)(p >> 3) * NN + ibn + (p & 7) * 8);
        }
        // all adj loads for the step up-front: max memory-level parallelism
        float av[4][8];
        #pragma unroll
        for (int kk = 0; kk < 4; ++kk)
            #pragma unroll
            for (int e = 0; e < 8; ++e)
                av[kk][e] = adj[(size_t)(ib + kk * 16 + half * 8 + e) * NN + gj];

        #pragma unroll
        for (int kk = 0; kk < 4; ++kk) {
            int kb = kk * 16 + half * 8;
            int gib = ib + kb;
            short8 bf[4];
            #pragma unroll
            for (int nt = 0; nt < 4; ++nt)
                bf[nt] = *(const short8*)(&htS[pb][(nt * 32 + (lane & 31)) * HTS + kb]);
            float4 e1a = *(const float4*)&e1S[s * KT + kb];
            float4 e1b = *(const float4*)&e1S[s * KT + kb + 4];
            float4 e2a = *(const float4*)&e2S[s * KT + kb];
            float4 e2b = *(const float4*)&e2S[s * KT + kb + 4];
            float e1v[8] = {e1a.x, e1a.y, e1a.z, e1a.w, e1b.x, e1b.y, e1b.z, e1b.w};
            float e2v[8] = {e2a.x, e2a.y, e2a.z, e2a.w, e2b.x, e2b.y, e2b.z, e2b.w};
            float pv[8];
            #pragma unroll
            for (int e = 0; e < 8; ++e) {
                float m1 = e1v[e] * ed1;            // e^{s+d}
                float m2 = e2v[e] * ed2;            // e^{0.2(s+d)}
                float ev = m1 > 1.0f ? m1 : m2;     // lrelu branch: t>0 <=> e^t>1
                pv[e] = (av[kk][e] != 0.f || (gib + e) == gj) ? ev : 0.f;
                dsum += pv[e];
            }
            short8 af = pack8_bf16(pv);
            #pragma unroll
            for (int nt = 0; nt < 4; ++nt)
                acc[nt] = __builtin_amdgcn_mfma_f32_32x32x16_bf16(af, bf[nt],
                                                                  acc[nt], 0, 0, 0);
        }
        // single barrier per step: readers of htS[pb^1] all finished before
        // the PREVIOUS barrier, so writing it here races with nothing.
        #pragma unroll
        for (int q = 0; q < 4; ++q) {
            int p = q * 256 + tid;
            *(short8*)(&htS[pb ^ 1][(p >> 3) * HTS + (p & 7) * 8]) = bv[q];
        }
        __syncthreads();
    }

    // partial C write (fp16): C/D layout col=lane&31, row=(r&3)+8*(r>>2)+4*half
    #pragma unroll
    for (int nt = 0; nt < 4; ++nt) {
        int c = nt * 32 + (lane & 31);
        #pragma unroll
        for (int r = 0; r < 16; ++r) {
            int row = (r & 3) + 8 * (r >> 2) + 4 * half;
            int j = j0 + w * 32 + row;
            pout[((size_t)ch * NN + j) * COUT + c] = (f16)acc[nt][r];
        }
    }
    float dall = dsum + __shfl_xor(dsum, 32, 64);  // halves cover disjoint k
    if (half == 0) pden[(size_t)ch * NN + gj] = dall;
}

// ---------------- Kernel C: reduce partials, normalize, bias --------------
__global__ __launch_bounds__(256) void gat_reduce(const f16* __restrict__ pout,
                                                  const float* __restrict__ pden,
                                                  const float* __restrict__ bias,
                                                  float* __restrict__ out) {
    int idx = blockIdx.x * 256 + threadIdx.x;
    int j = idx >> 4;
    int c8 = (idx & 15) * 8;
    f16x8 pv[CH];
    #pragma unroll
    for (int ch = 0; ch < CH; ++ch)
        pv[ch] = *(const f16x8*)(pout + ((size_t)ch * NN + j) * COUT + c8);
    float den = 0.f;
    #pragma unroll
    for (int ch = 0; ch < CH; ++ch) den += pden[(size_t)ch * NN + j];
    float s[8] = {};
    #pragma unroll
    for (int ch = 0; ch < CH; ++ch)
        #pragma unroll
        for (int q = 0; q < 8; ++q) s[q] += (float)pv[ch][q];
    float inv = 1.0f / den;
    float4 b0 = *(const float4*)&bias[c8];
    float4 b1 = *(const float4*)&bias[c8 + 4];
    float4 o0 = make_float4(s[0] * inv + b0.x, s[1] * inv + b0.y,
                            s[2] * inv + b0.z, s[3] * inv + b0.w);
    float4 o1 = make_float4(s[4] * inv + b1.x, s[5] * inv + b1.y,
                            s[6] * inv + b1.z, s[7] * inv + b1.w);
    *(float4*)&out[(size_t)j * COUT + c8]     = o0;
    *(float4*)&out[(size_t)j * COUT + c8 + 4] = o1;
}

extern "C" void kernel_launch(void* const* d_in, const int* in_sizes, int n_in,
                              void* d_out, int out_size, void* d_ws, size_t ws_size,
                              hipStream_t stream) {
    const float* x       = (const float*)d_in[0];
    const float* adj     = (const float*)d_in[1];
    const float* W       = (const float*)d_in[2];
    const float* att_src = (const float*)d_in[3];
    const float* att_dst = (const float*)d_in[4];
    const float* bias    = (const float*)d_in[5];
    float* out = (float*)d_out;

    u16*   h_t  = (u16*)d_ws;                                   // 2 MB
    float* es1  = (float*)((char*)d_ws + (size_t)2 * 1024 * 1024);
    float* es2  = es1 + NN;                                     // 32 KB each
    float* adw  = es2 + NN;                                     // 32 KB
    float* pden = adw + NN;                                     // 256 KB
    f16*   pout = (f16*)(pden + (size_t)CH * NN);               // 16 MB

    gemm_h    <<<NN / GR, 256, 0, stream>>>(x, W, att_src, att_dst, h_t, es1, es2, adw);
    gat_mm    <<<64 * CH, 256, 0, stream>>>(adj, h_t, es1, es2, adw, pout, pden);
    gat_reduce<<<NN * COUT / 8 / 256, 256, 0, stream>>>(pout, pden, bias, out);
}